// Round 2
// baseline (1022.744 us; speedup 1.0000x reference)
//
#include <hip/hip_runtime.h>
#include <hip/hip_bf16.h>

// Y[N, 640] = A[N,128] @ [ interleaved basis-cols (512: c = o*4+b) | root (128) ]
// A: layer1 = entity_context_tab[entity[n]] (fp32 gather); layer2 = fp32 X1.
// LDS: As fp32 64x64 (XOR-swizzled), Bs fp32 64x128. 48KB -> 2 blocks/CU.
template<bool LAYER1>
__global__ __launch_bounds__(256, 2) void gemm_kernel(
    const float* __restrict__ A,        // layer1: entity_context_tab; layer2: X1
    const int* __restrict__ entity,     // layer1 gather indices (nullptr for layer2)
    const float* __restrict__ basis,    // [4,128,128] fp32
    const float* __restrict__ root,     // [128,128] fp32
    float* __restrict__ Y, int N)
{
    __shared__ float As[64 * 64];
    __shared__ float Bs[64 * 128];
    const int tid  = threadIdx.x;
    const int row0 = blockIdx.x * 64;
    const int c0   = blockIdx.y * 128;

    const int rg = tid >> 4;        // 0..15 -> 4 rows each
    const int cg = tid & 15;        // 0..15 -> 8 cols each
    const int r0 = rg << 2;
    const int sw = (rg & 7) << 3;   // read-side swizzle (matches store: r>>2 == rg)

    float acc[4][8];
    #pragma unroll
    for (int j = 0; j < 4; ++j)
        #pragma unroll
        for (int c = 0; c < 8; ++c) acc[j][c] = 0.0f;

    #pragma unroll
    for (int kc = 0; kc < 2; ++kc) {
        const int k0 = kc * 64;
        if (kc) __syncthreads();    // protect LDS reuse between chunks

        // A chunk: 64 rows x 64 k, coalesced global, swizzled LDS store
        #pragma unroll
        for (int i = 0; i < 16; ++i) {
            int idx = tid + i * 256;
            int r = idx >> 6, k = idx & 63;
            int gr = row0 + r;
            float v = 0.0f;
            if (gr < N) {
                int srow = LAYER1 ? entity[gr] : gr;
                v = A[(size_t)srow * 128 + k0 + k];
            }
            As[r * 64 + (k ^ (((r >> 2) & 7) << 3))] = v;
        }
        // B chunk: 64 k x 128 cols; interleaved mapping for global col < 512
        #pragma unroll
        for (int i = 0; i < 32; ++i) {
            int idx = tid + i * 256;
            int kl = idx >> 7, c = idx & 127;
            int kgl = k0 + kl;
            int cgc = c0 + c;
            float w;
            if (cgc < 512) w = basis[((cgc & 3) << 14) + (kgl << 7) + (cgc >> 2)];
            else           w = root[(kgl << 7) + (cgc - 512)];
            Bs[(kl << 7) + c] = w;
        }
        __syncthreads();

        #pragma unroll 4
        for (int k = 0; k < 64; ++k) {
            int ks = k ^ sw;
            float a0 = As[(r0 + 0) * 64 + ks];
            float a1 = As[(r0 + 1) * 64 + ks];
            float a2 = As[(r0 + 2) * 64 + ks];
            float a3 = As[(r0 + 3) * 64 + ks];
            float4 b0 = *(const float4*)&Bs[(k << 7) + (cg << 3)];
            float4 b1 = *(const float4*)&Bs[(k << 7) + (cg << 3) + 4];
            float a[4] = {a0, a1, a2, a3};
            float b[8] = {b0.x, b0.y, b0.z, b0.w, b1.x, b1.y, b1.z, b1.w};
            #pragma unroll
            for (int j = 0; j < 4; ++j)
                #pragma unroll
                for (int c = 0; c < 8; ++c)
                    acc[j][c] = fmaf(a[j], b[c], acc[j][c]);
        }
    }

    #pragma unroll
    for (int j = 0; j < 4; ++j) {
        int gr = row0 + r0 + j;
        if (gr < N) {
            float* yp = Y + (size_t)gr * 640 + c0 + (cg << 3);
            *(float4*)yp       = make_float4(acc[j][0], acc[j][1], acc[j][2], acc[j][3]);
            *(float4*)(yp + 4) = make_float4(acc[j][4], acc[j][5], acc[j][6], acc[j][7]);
        }
    }
}

// per edge: msg[o] = norm * sum_b att[et,b] * Y[src, o*4+b]; atomic into Agg[dst], cnt[dst]
__global__ __launch_bounds__(256) void scatter_kernel(
    const float* __restrict__ Y,
    const int* __restrict__ edge_index,
    const int* __restrict__ edge_type,
    const float* __restrict__ edge_norm,
    const float* __restrict__ att,      // [R,4] fp32
    float* __restrict__ Agg, float* __restrict__ cnt, int E)
{
    int e = blockIdx.x * 2 + (threadIdx.x >> 7);
    if (e >= E) return;
    int o   = threadIdx.x & 127;
    int src = edge_index[e];
    int dst = edge_index[E + e];
    int et  = edge_type[e];
    float norm = edge_norm[e];
    float4 a = *(const float4*)(att + (size_t)et * 4);
    float4 y = *(const float4*)&Y[(size_t)src * 640 + o * 4];
    float msg = norm * (a.x * y.x + a.y * y.y + a.z * y.z + a.w * y.w);
    atomicAdd(&Agg[(size_t)dst * 128 + o], msg);
    if (o == 0) atomicAdd(&cnt[dst], 1.0f);
}

// X := relu(Agg/max(cnt,1) + Y[:,512:640] + bias), in place into Agg
__global__ __launch_bounds__(256) void finalize_kernel(
    float* __restrict__ Agg, const float* __restrict__ cnt,
    const float* __restrict__ Y, const float* __restrict__ bias, int N)
{
    int n = blockIdx.x * 2 + (threadIdx.x >> 7);
    if (n >= N) return;
    int o = threadIdx.x & 127;
    float c = cnt[n];
    float v = Agg[(size_t)n * 128 + o] / fmaxf(c, 1.0f)
            + Y[(size_t)n * 640 + 512 + o] + bias[o];
    Agg[(size_t)n * 128 + o] = fmaxf(v, 0.0f);
}

// R2 = relu(DAD @ tab @ W), one block per relation row
__global__ __launch_bounds__(128) void relctx_kernel(
    const float* __restrict__ DAD,
    const float* __restrict__ tab,
    const float* __restrict__ W,
    float* __restrict__ R2, int NR)
{
    int r = blockIdx.x;
    int o = threadIdx.x;
    float s = 0.0f;
    for (int j = 0; j < NR; ++j)
        s = fmaf(DAD[r * NR + j], tab[j * 128 + o], s);
    __shared__ float r1s[128];
    r1s[o] = s;
    __syncthreads();
    float s2 = 0.0f;
    #pragma unroll 8
    for (int k = 0; k < 128; ++k)
        s2 = fmaf(r1s[k], W[k * 128 + o], s2);
    R2[r * 128 + o] = fmaxf(s2, 0.0f);
}

// out[p,s,:]: gated mix of embeddings and context
__global__ __launch_bounds__(256) void output_kernel(
    const int* __restrict__ samples,
    const float* __restrict__ gate_e,
    const float* __restrict__ gate_r,
    const float* __restrict__ ent_emb,
    const float* __restrict__ rel_emb,
    const float* __restrict__ ctx2,
    const float* __restrict__ relctx,
    float* __restrict__ out, int S)
{
    int s = blockIdx.x * 2 + (threadIdx.x >> 7);
    if (s >= S) return;
    int p = blockIdx.y;
    int o = threadIdx.x & 127;
    float v;
    if (p == 1) {
        int idx = samples[s * 3 + 1];
        float g = 1.0f / (1.0f + __expf(-gate_r[o]));
        v = g * rel_emb[idx * 128 + o] + (1.0f - g) * relctx[idx * 128 + o];
    } else {
        int idx = samples[s * 3 + (p == 0 ? 0 : 2)];
        float g = 1.0f / (1.0f + __expf(-gate_e[o]));
        v = g * ent_emb[(size_t)idx * 128 + o] + (1.0f - g) * ctx2[(size_t)idx * 128 + o];
    }
    out[(size_t)p * S * 128 + (size_t)s * 128 + o] = v;
}

extern "C" void kernel_launch(void* const* d_in, const int* in_sizes, int n_in,
                              void* d_out, int out_size, void* d_ws, size_t ws_size,
                              hipStream_t stream)
{
    const int*   entity     = (const int*)d_in[0];
    const int*   edge_index = (const int*)d_in[1];
    const int*   edge_type  = (const int*)d_in[2];
    const float* edge_norm  = (const float*)d_in[3];
    const int*   samples    = (const int*)d_in[4];
    const float* DAD        = (const float*)d_in[5];
    const float* ent_emb    = (const float*)d_in[6];
    const float* rel_emb    = (const float*)d_in[7];
    const float* ent_tab    = (const float*)d_in[8];
    const float* rel_tab    = (const float*)d_in[9];
    const float* Wrel       = (const float*)d_in[10];
    const float* gate_e     = (const float*)d_in[11];
    const float* gate_r     = (const float*)d_in[12];
    const float* basis1     = (const float*)d_in[13];
    const float* att1       = (const float*)d_in[14];
    const float* root1      = (const float*)d_in[15];
    const float* bias1      = (const float*)d_in[16];
    const float* basis2     = (const float*)d_in[17];
    const float* att2       = (const float*)d_in[18];
    const float* root2      = (const float*)d_in[19];
    const float* bias2      = (const float*)d_in[20];

    const int N  = in_sizes[0];        // 50000
    const int E  = in_sizes[2];        // 200000
    const int S  = in_sizes[4] / 3;    // 20000
    const int NR = in_sizes[9] / 128;  // 200

    float* ws  = (float*)d_ws;
    float* Y   = ws;                              // [N,640] fp32  (128 MB)
    float* Agg = Y + (size_t)N * 640;             // [N,128] fp32, reused as X1/ctx2
    float* cnt = Agg + (size_t)N * 128;           // [N] fp32
    float* Rc  = cnt + N;                         // [NR,128] fp32

    dim3 ggrid((N + 63) / 64, 5);
    size_t aggBytes = ((size_t)N * 128 + N) * sizeof(float);

    // ---- layer 1 ----
    hipMemsetAsync(Agg, 0, aggBytes, stream);
    gemm_kernel<true ><<<ggrid, 256, 0, stream>>>(ent_tab, entity, basis1, root1, Y, N);
    scatter_kernel <<<(E + 1) / 2, 256, 0, stream>>>(Y, edge_index, edge_type, edge_norm, att1, Agg, cnt, E);
    finalize_kernel<<<(N + 1) / 2, 256, 0, stream>>>(Agg, cnt, Y, bias1, N);

    // ---- layer 2 (X1 lives in Agg; GEMM reads it before the memset) ----
    gemm_kernel<false><<<ggrid, 256, 0, stream>>>(Agg, nullptr, basis2, root2, Y, N);
    hipMemsetAsync(Agg, 0, aggBytes, stream);
    scatter_kernel <<<(E + 1) / 2, 256, 0, stream>>>(Y, edge_index, edge_type, edge_norm, att2, Agg, cnt, E);
    finalize_kernel<<<(N + 1) / 2, 256, 0, stream>>>(Agg, cnt, Y, bias2, N);

    // ---- relation context (tiny) ----
    relctx_kernel<<<NR, 128, 0, stream>>>(DAD, rel_tab, Wrel, Rc, NR);

    // ---- gated gather ----
    output_kernel<<<dim3((S + 1) / 2, 3), 256, 0, stream>>>(
        samples, gate_e, gate_r, ent_emb, rel_emb, Agg, Rc, (float*)d_out, S);
}

// Round 3
// 675.914 us; speedup vs baseline: 1.5131x; 1.5131x over previous
//
#include <hip/hip_runtime.h>
#include <hip/hip_bf16.h>

// Y[N, 640] = A[N,128] @ [ interleaved basis-cols (512: c = o*4+b) | root (128) ]
// A: layer1 = entity_context_tab[entity[n]] (fp32 gather); layer2 = fp32 X1.
// 128x128 tile, 256 threads, 8x8 per-thread register block, K-chunk 32.
// LDS: As [k][m] stride 132 (conflict-free b128 reads, 16B aligned), Bs [k][n].
template<bool LAYER1>
__global__ __launch_bounds__(256, 4) void gemm_kernel(
    const float* __restrict__ A,        // layer1: entity_context_tab; layer2: X1
    const int* __restrict__ entity,     // layer1 gather indices (nullptr for layer2)
    const float* __restrict__ basis,    // [4,128,128] fp32
    const float* __restrict__ root,     // [128,128] fp32
    float* __restrict__ Y, int N)
{
    __shared__ float As[32 * 132];      // [k][m], padded stride 132
    __shared__ float Bs[32 * 128];      // [k][n]
    __shared__ int   ent_s[128];

    const int tid  = threadIdx.x;
    const int row0 = blockIdx.x * 128;
    const int c0   = blockIdx.y * 128;

    if (LAYER1) {
        if (tid < 128) {
            int gr = row0 + tid;
            ent_s[tid] = (gr < N) ? entity[gr] : 0;
        }
    }

    const int rg = tid >> 4;            // 0..15 -> rows rg*8..rg*8+7
    const int cg = tid & 15;            // 0..15 -> cols cg*8..cg*8+7

    float acc[8][8];
    #pragma unroll
    for (int j = 0; j < 8; ++j)
        #pragma unroll
        for (int c = 0; c < 8; ++c) acc[j][c] = 0.0f;

    if (LAYER1) __syncthreads();        // ent_s visible before A staging

    #pragma unroll
    for (int kc = 0; kc < 4; ++kc) {
        const int k0 = kc * 32;
        if (kc) __syncthreads();        // protect LDS reuse between chunks

        // A chunk: 128 rows x 32 k; coalesced float4 global, transposed LDS store.
        // Store banks: addr = (kv+j)*132 + r -> within 8-lane group kv steps 4,
        // bank steps 16 -> <=4-way on b32 stores (cheap, 16 stores/thread/chunk).
        #pragma unroll
        for (int i = 0; i < 4; ++i) {
            int idx = tid + i * 256;
            int r   = idx >> 3;          // 0..127
            int kv  = (idx & 7) << 2;    // 0,4,...,28
            int gr  = row0 + r;
            float4 v = make_float4(0.f, 0.f, 0.f, 0.f);
            if (gr < N) {
                int srow = LAYER1 ? ent_s[r] : gr;
                v = *(const float4*)&A[(size_t)srow * 128 + k0 + kv];
            }
            As[(kv + 0) * 132 + r] = v.x;
            As[(kv + 1) * 132 + r] = v.y;
            As[(kv + 2) * 132 + r] = v.z;
            As[(kv + 3) * 132 + r] = v.w;
        }
        // B chunk: 32 k x 128 n; interleaved mapping for global col < 512.
        // Per-component loads are lane-coalesced (c>>2 consecutive); B is L2-hot.
        #pragma unroll
        for (int i = 0; i < 4; ++i) {
            int idx = tid + i * 256;
            int kl  = idx >> 5;          // 0..31
            int nv  = (idx & 31) << 2;   // 0,4,...,124
            int kg  = k0 + kl;
            int cgc = c0 + nv;
            float4 w;
            if (cgc < 512) {
                w.x = basis[(((cgc + 0) & 3) << 14) + (kg << 7) + ((cgc + 0) >> 2)];
                w.y = basis[(((cgc + 1) & 3) << 14) + (kg << 7) + ((cgc + 1) >> 2)];
                w.z = basis[(((cgc + 2) & 3) << 14) + (kg << 7) + ((cgc + 2) >> 2)];
                w.w = basis[(((cgc + 3) & 3) << 14) + (kg << 7) + ((cgc + 3) >> 2)];
            } else {
                w = *(const float4*)&root[(kg << 7) + (cgc - 512)];
            }
            *(float4*)&Bs[kl * 128 + nv] = w;
        }
        __syncthreads();

        #pragma unroll 4
        for (int k = 0; k < 32; ++k) {
            float a[8], b[8];
            *(float4*)&a[0] = *(const float4*)&As[k * 132 + rg * 8];
            *(float4*)&a[4] = *(const float4*)&As[k * 132 + rg * 8 + 4];
            *(float4*)&b[0] = *(const float4*)&Bs[k * 128 + cg * 8];
            *(float4*)&b[4] = *(const float4*)&Bs[k * 128 + cg * 8 + 4];
            #pragma unroll
            for (int j = 0; j < 8; ++j)
                #pragma unroll
                for (int c = 0; c < 8; ++c)
                    acc[j][c] = fmaf(a[j], b[c], acc[j][c]);
        }
    }

    #pragma unroll
    for (int j = 0; j < 8; ++j) {
        int gr = row0 + rg * 8 + j;
        if (gr < N) {
            float* yp = Y + (size_t)gr * 640 + c0 + cg * 8;
            *(float4*)yp       = make_float4(acc[j][0], acc[j][1], acc[j][2], acc[j][3]);
            *(float4*)(yp + 4) = make_float4(acc[j][4], acc[j][5], acc[j][6], acc[j][7]);
        }
    }
}

// per edge: msg[o] = norm * sum_b att[et,b] * Y[src, o*4+b]; atomic into Agg[dst], cnt[dst]
__global__ __launch_bounds__(256) void scatter_kernel(
    const float* __restrict__ Y,
    const int* __restrict__ edge_index,
    const int* __restrict__ edge_type,
    const float* __restrict__ edge_norm,
    const float* __restrict__ att,      // [R,4] fp32
    float* __restrict__ Agg, float* __restrict__ cnt, int E)
{
    int e = blockIdx.x * 2 + (threadIdx.x >> 7);
    if (e >= E) return;
    int o   = threadIdx.x & 127;
    int src = edge_index[e];
    int dst = edge_index[E + e];
    int et  = edge_type[e];
    float norm = edge_norm[e];
    float4 a = *(const float4*)(att + (size_t)et * 4);
    float4 y = *(const float4*)&Y[(size_t)src * 640 + o * 4];
    float msg = norm * (a.x * y.x + a.y * y.y + a.z * y.z + a.w * y.w);
    atomicAdd(&Agg[(size_t)dst * 128 + o], msg);
    if (o == 0) atomicAdd(&cnt[dst], 1.0f);
}

// X := relu(Agg/max(cnt,1) + Y[:,512:640] + bias), in place into Agg
__global__ __launch_bounds__(256) void finalize_kernel(
    float* __restrict__ Agg, const float* __restrict__ cnt,
    const float* __restrict__ Y, const float* __restrict__ bias, int N)
{
    int n = blockIdx.x * 2 + (threadIdx.x >> 7);
    if (n >= N) return;
    int o = threadIdx.x & 127;
    float c = cnt[n];
    float v = Agg[(size_t)n * 128 + o] / fmaxf(c, 1.0f)
            + Y[(size_t)n * 640 + 512 + o] + bias[o];
    Agg[(size_t)n * 128 + o] = fmaxf(v, 0.0f);
}

// R2 = relu(DAD @ tab @ W), one block per relation row
__global__ __launch_bounds__(128) void relctx_kernel(
    const float* __restrict__ DAD,
    const float* __restrict__ tab,
    const float* __restrict__ W,
    float* __restrict__ R2, int NR)
{
    int r = blockIdx.x;
    int o = threadIdx.x;
    float s = 0.0f;
    for (int j = 0; j < NR; ++j)
        s = fmaf(DAD[r * NR + j], tab[j * 128 + o], s);
    __shared__ float r1s[128];
    r1s[o] = s;
    __syncthreads();
    float s2 = 0.0f;
    #pragma unroll 8
    for (int k = 0; k < 128; ++k)
        s2 = fmaf(r1s[k], W[k * 128 + o], s2);
    R2[r * 128 + o] = fmaxf(s2, 0.0f);
}

// out[p,s,:]: gated mix of embeddings and context
__global__ __launch_bounds__(256) void output_kernel(
    const int* __restrict__ samples,
    const float* __restrict__ gate_e,
    const float* __restrict__ gate_r,
    const float* __restrict__ ent_emb,
    const float* __restrict__ rel_emb,
    const float* __restrict__ ctx2,
    const float* __restrict__ relctx,
    float* __restrict__ out, int S)
{
    int s = blockIdx.x * 2 + (threadIdx.x >> 7);
    if (s >= S) return;
    int p = blockIdx.y;
    int o = threadIdx.x & 127;
    float v;
    if (p == 1) {
        int idx = samples[s * 3 + 1];
        float g = 1.0f / (1.0f + __expf(-gate_r[o]));
        v = g * rel_emb[idx * 128 + o] + (1.0f - g) * relctx[idx * 128 + o];
    } else {
        int idx = samples[s * 3 + (p == 0 ? 0 : 2)];
        float g = 1.0f / (1.0f + __expf(-gate_e[o]));
        v = g * ent_emb[(size_t)idx * 128 + o] + (1.0f - g) * ctx2[(size_t)idx * 128 + o];
    }
    out[(size_t)p * S * 128 + (size_t)s * 128 + o] = v;
}

extern "C" void kernel_launch(void* const* d_in, const int* in_sizes, int n_in,
                              void* d_out, int out_size, void* d_ws, size_t ws_size,
                              hipStream_t stream)
{
    const int*   entity     = (const int*)d_in[0];
    const int*   edge_index = (const int*)d_in[1];
    const int*   edge_type  = (const int*)d_in[2];
    const float* edge_norm  = (const float*)d_in[3];
    const int*   samples    = (const int*)d_in[4];
    const float* DAD        = (const float*)d_in[5];
    const float* ent_emb    = (const float*)d_in[6];
    const float* rel_emb    = (const float*)d_in[7];
    const float* ent_tab    = (const float*)d_in[8];
    const float* rel_tab    = (const float*)d_in[9];
    const float* Wrel       = (const float*)d_in[10];
    const float* gate_e     = (const float*)d_in[11];
    const float* gate_r     = (const float*)d_in[12];
    const float* basis1     = (const float*)d_in[13];
    const float* att1       = (const float*)d_in[14];
    const float* root1      = (const float*)d_in[15];
    const float* bias1      = (const float*)d_in[16];
    const float* basis2     = (const float*)d_in[17];
    const float* att2       = (const float*)d_in[18];
    const float* root2      = (const float*)d_in[19];
    const float* bias2      = (const float*)d_in[20];

    const int N  = in_sizes[0];        // 50000
    const int E  = in_sizes[2];        // 200000
    const int S  = in_sizes[4] / 3;    // 20000
    const int NR = in_sizes[9] / 128;  // 200

    float* ws  = (float*)d_ws;
    float* Y   = ws;                              // [N,640] fp32  (128 MB)
    float* Agg = Y + (size_t)N * 640;             // [N,128] fp32, reused as X1/ctx2
    float* cnt = Agg + (size_t)N * 128;           // [N] fp32
    float* Rc  = cnt + N;                         // [NR,128] fp32

    dim3 ggrid((N + 127) / 128, 5);
    size_t aggBytes = ((size_t)N * 128 + N) * sizeof(float);

    // ---- layer 1 ----
    hipMemsetAsync(Agg, 0, aggBytes, stream);
    gemm_kernel<true ><<<ggrid, 256, 0, stream>>>(ent_tab, entity, basis1, root1, Y, N);
    scatter_kernel <<<(E + 1) / 2, 256, 0, stream>>>(Y, edge_index, edge_type, edge_norm, att1, Agg, cnt, E);
    finalize_kernel<<<(N + 1) / 2, 256, 0, stream>>>(Agg, cnt, Y, bias1, N);

    // ---- layer 2 (X1 lives in Agg; GEMM reads it before the memset) ----
    gemm_kernel<false><<<ggrid, 256, 0, stream>>>(Agg, nullptr, basis2, root2, Y, N);
    hipMemsetAsync(Agg, 0, aggBytes, stream);
    scatter_kernel <<<(E + 1) / 2, 256, 0, stream>>>(Y, edge_index, edge_type, edge_norm, att2, Agg, cnt, E);
    finalize_kernel<<<(N + 1) / 2, 256, 0, stream>>>(Agg, cnt, Y, bias2, N);

    // ---- relation context (tiny) ----
    relctx_kernel<<<NR, 128, 0, stream>>>(DAD, rel_tab, Wrel, Rc, NR);

    // ---- gated gather ----
    output_kernel<<<dim3((S + 1) / 2, 3), 256, 0, stream>>>(
        samples, gate_e, gate_r, ent_emb, rel_emb, Agg, Rc, (float*)d_out, S);
}

// Round 4
// 631.301 us; speedup vs baseline: 1.6201x; 1.0707x over previous
//
#include <hip/hip_runtime.h>
#include <hip/hip_bf16.h>

// ---------------- GEMM: Y[N,640] = A[N,128] @ [interleaved basis (512) | root (128)]
// 128x128 tile, 256 threads, 8x8 per-thread block split as cols {cg*4, 64+cg*4}
// so every ds_read_b128 is word-stride-4 across 16 lanes -> 2 rows/bank -> conflict-free.
template<bool LAYER1>
__global__ __launch_bounds__(256, 4) void gemm_kernel(
    const float* __restrict__ A,
    const int* __restrict__ entity,
    const float* __restrict__ basis,    // [4,128,128]
    const float* __restrict__ root,     // [128,128]
    float* __restrict__ Y, int N)
{
    __shared__ float As[32 * 132];      // [k][m], padded stride 132
    __shared__ float Bs[32 * 128];      // [k][n]
    __shared__ int   ent_s[128];

    const int tid  = threadIdx.x;
    const int row0 = blockIdx.x * 128;
    const int c0   = blockIdx.y * 128;

    if (LAYER1) {
        if (tid < 128) {
            int gr = row0 + tid;
            ent_s[tid] = (gr < N) ? entity[gr] : 0;
        }
    }

    const int rg = tid >> 4;            // rows rg*8..rg*8+7
    const int cg = tid & 15;
    const int cA = cg << 2;             // cols cA..cA+3 and 64+cA..64+cA+3

    float acc[8][8];
    #pragma unroll
    for (int j = 0; j < 8; ++j)
        #pragma unroll
        for (int c = 0; c < 8; ++c) acc[j][c] = 0.0f;

    if (LAYER1) __syncthreads();

    #pragma unroll
    for (int kc = 0; kc < 4; ++kc) {
        const int k0 = kc * 32;
        if (kc) __syncthreads();

        #pragma unroll
        for (int i = 0; i < 4; ++i) {
            int idx = tid + i * 256;
            int r   = idx >> 3;
            int kv  = (idx & 7) << 2;
            int gr  = row0 + r;
            float4 v = make_float4(0.f, 0.f, 0.f, 0.f);
            if (gr < N) {
                int srow = LAYER1 ? ent_s[r] : gr;
                v = *(const float4*)&A[(size_t)srow * 128 + k0 + kv];
            }
            As[(kv + 0) * 132 + r] = v.x;
            As[(kv + 1) * 132 + r] = v.y;
            As[(kv + 2) * 132 + r] = v.z;
            As[(kv + 3) * 132 + r] = v.w;
        }
        #pragma unroll
        for (int i = 0; i < 4; ++i) {
            int idx = tid + i * 256;
            int kl  = idx >> 5;
            int nv  = (idx & 31) << 2;
            int kg  = k0 + kl;
            int cgc = c0 + nv;
            float4 w;
            if (cgc < 512) {
                w.x = basis[(((cgc + 0) & 3) << 14) + (kg << 7) + ((cgc + 0) >> 2)];
                w.y = basis[(((cgc + 1) & 3) << 14) + (kg << 7) + ((cgc + 1) >> 2)];
                w.z = basis[(((cgc + 2) & 3) << 14) + (kg << 7) + ((cgc + 2) >> 2)];
                w.w = basis[(((cgc + 3) & 3) << 14) + (kg << 7) + ((cgc + 3) >> 2)];
            } else {
                w = *(const float4*)&root[(kg << 7) + (cgc - 512)];
            }
            *(float4*)&Bs[kl * 128 + nv] = w;
        }
        __syncthreads();

        #pragma unroll 4
        for (int k = 0; k < 32; ++k) {
            float a[8], b[8];
            *(float4*)&a[0] = *(const float4*)&As[k * 132 + rg * 8];
            *(float4*)&a[4] = *(const float4*)&As[k * 132 + rg * 8 + 4];
            *(float4*)&b[0] = *(const float4*)&Bs[k * 128 + cA];
            *(float4*)&b[4] = *(const float4*)&Bs[k * 128 + 64 + cA];
            #pragma unroll
            for (int j = 0; j < 8; ++j)
                #pragma unroll
                for (int c = 0; c < 8; ++c)
                    acc[j][c] = fmaf(a[j], b[c], acc[j][c]);
        }
    }

    #pragma unroll
    for (int j = 0; j < 8; ++j) {
        int gr = row0 + rg * 8 + j;
        if (gr < N) {
            float* yp = Y + (size_t)gr * 640 + c0;
            *(float4*)(yp + cA)      = make_float4(acc[j][0], acc[j][1], acc[j][2], acc[j][3]);
            *(float4*)(yp + 64 + cA) = make_float4(acc[j][4], acc[j][5], acc[j][6], acc[j][7]);
        }
    }
}

// ---------------- CSR build ----------------
__global__ __launch_bounds__(256) void hist_kernel(
    const int* __restrict__ edge_index, int* __restrict__ deg, int E)
{
    int e = blockIdx.x * 256 + threadIdx.x;
    if (e < E) atomicAdd(&deg[edge_index[E + e]], 1);
}

// one-block exclusive scan over deg[0..N) -> row_start, cursor; row_start[N] = total
__global__ __launch_bounds__(1024) void scan_kernel(
    const int* __restrict__ deg, int* __restrict__ row_start,
    int* __restrict__ cursor, int N)
{
    __shared__ int wtot[16];
    __shared__ int woff[16];
    __shared__ int carry;
    const int tid = threadIdx.x, lane = tid & 63, wid = tid >> 6;
    if (tid == 0) carry = 0;
    __syncthreads();
    const int nChunks = (N + 1023) / 1024;
    for (int c = 0; c < nChunks; ++c) {
        int i = c * 1024 + tid;
        int v = (i < N) ? deg[i] : 0;
        int x = v;
        #pragma unroll
        for (int d = 1; d < 64; d <<= 1) {
            int t = __shfl_up(x, d, 64);
            if (lane >= d) x += t;
        }
        if (lane == 63) wtot[wid] = x;
        __syncthreads();
        if (wid == 0 && lane < 16) {
            int s = wtot[lane];
            int y = s;
            #pragma unroll
            for (int d = 1; d < 16; d <<= 1) {
                int t = __shfl_up(y, d, 16);
                if (lane >= d) y += t;
            }
            woff[lane] = y - s;             // exclusive wave offset
            if (lane == 15) wtot[15] = y;   // block total (all reads of wtot done)
        }
        __syncthreads();
        if (i < N) {
            int rs = carry + woff[wid] + (x - v);
            row_start[i] = rs;
            cursor[i]    = rs;
        }
        __syncthreads();
        if (tid == 0) carry += wtot[15];
        __syncthreads();
    }
    if (tid == 0) row_start[N] = carry;
}

// fill: reorder (src, et, norm) by destination bucket
__global__ __launch_bounds__(256) void fill_kernel(
    const int* __restrict__ edge_index, const int* __restrict__ edge_type,
    const float* __restrict__ edge_norm, int* __restrict__ cursor,
    int* __restrict__ src_s, int* __restrict__ et_s, float* __restrict__ norm_s, int E)
{
    int e = blockIdx.x * 256 + threadIdx.x;
    if (e >= E) return;
    int dst = edge_index[E + e];
    int pos = atomicAdd(&cursor[dst], 1);
    src_s[pos]  = edge_index[e];
    et_s[pos]   = edge_type[e];
    norm_s[pos] = edge_norm[e];
}

// ---------------- gather: X[n] = relu(mean_e msg + Y[n,512:640] + bias) ----------------
__global__ __launch_bounds__(256) void gather_kernel(
    const float* __restrict__ Y,
    const int* __restrict__ row_start,
    const int* __restrict__ src_s, const int* __restrict__ et_s,
    const float* __restrict__ norm_s,
    const float* __restrict__ att,      // [R,4]
    const float* __restrict__ bias,
    float* __restrict__ X, int N)
{
    int n = blockIdx.x * 2 + (threadIdx.x >> 7);
    if (n >= N) return;
    int o = threadIdx.x & 127;
    int s0 = row_start[n], s1 = row_start[n + 1];
    float acc = 0.0f;
    for (int p = s0; p < s1; ++p) {
        int   src  = src_s[p];
        int   et   = et_s[p];
        float norm = norm_s[p];
        float4 a = *(const float4*)(att + (size_t)et * 4);
        float4 y = *(const float4*)&Y[(size_t)src * 640 + o * 4];
        acc += norm * (a.x * y.x + a.y * y.y + a.z * y.z + a.w * y.w);
    }
    float cnt = fmaxf((float)(s1 - s0), 1.0f);
    float v = acc / cnt + Y[(size_t)n * 640 + 512 + o] + bias[o];
    X[(size_t)n * 128 + o] = fmaxf(v, 0.0f);
}

// ---------------- relation context (tiny) ----------------
__global__ __launch_bounds__(128) void relctx_kernel(
    const float* __restrict__ DAD,
    const float* __restrict__ tab,
    const float* __restrict__ W,
    float* __restrict__ R2, int NR)
{
    int r = blockIdx.x;
    int o = threadIdx.x;
    float s = 0.0f;
    for (int j = 0; j < NR; ++j)
        s = fmaf(DAD[r * NR + j], tab[j * 128 + o], s);
    __shared__ float r1s[128];
    r1s[o] = s;
    __syncthreads();
    float s2 = 0.0f;
    #pragma unroll 8
    for (int k = 0; k < 128; ++k)
        s2 = fmaf(r1s[k], W[k * 128 + o], s2);
    R2[r * 128 + o] = fmaxf(s2, 0.0f);
}

// ---------------- gated output ----------------
__global__ __launch_bounds__(256) void output_kernel(
    const int* __restrict__ samples,
    const float* __restrict__ gate_e,
    const float* __restrict__ gate_r,
    const float* __restrict__ ent_emb,
    const float* __restrict__ rel_emb,
    const float* __restrict__ ctx2,
    const float* __restrict__ relctx,
    float* __restrict__ out, int S)
{
    int s = blockIdx.x * 2 + (threadIdx.x >> 7);
    if (s >= S) return;
    int p = blockIdx.y;
    int o = threadIdx.x & 127;
    float v;
    if (p == 1) {
        int idx = samples[s * 3 + 1];
        float g = 1.0f / (1.0f + __expf(-gate_r[o]));
        v = g * rel_emb[idx * 128 + o] + (1.0f - g) * relctx[idx * 128 + o];
    } else {
        int idx = samples[s * 3 + (p == 0 ? 0 : 2)];
        float g = 1.0f / (1.0f + __expf(-gate_e[o]));
        v = g * ent_emb[(size_t)idx * 128 + o] + (1.0f - g) * ctx2[(size_t)idx * 128 + o];
    }
    out[(size_t)p * S * 128 + (size_t)s * 128 + o] = v;
}

extern "C" void kernel_launch(void* const* d_in, const int* in_sizes, int n_in,
                              void* d_out, int out_size, void* d_ws, size_t ws_size,
                              hipStream_t stream)
{
    const int*   entity     = (const int*)d_in[0];
    const int*   edge_index = (const int*)d_in[1];
    const int*   edge_type  = (const int*)d_in[2];
    const float* edge_norm  = (const float*)d_in[3];
    const int*   samples    = (const int*)d_in[4];
    const float* DAD        = (const float*)d_in[5];
    const float* ent_emb    = (const float*)d_in[6];
    const float* rel_emb    = (const float*)d_in[7];
    const float* ent_tab    = (const float*)d_in[8];
    const float* rel_tab    = (const float*)d_in[9];
    const float* Wrel       = (const float*)d_in[10];
    const float* gate_e     = (const float*)d_in[11];
    const float* gate_r     = (const float*)d_in[12];
    const float* basis1     = (const float*)d_in[13];
    const float* att1       = (const float*)d_in[14];
    const float* root1      = (const float*)d_in[15];
    const float* bias1      = (const float*)d_in[16];
    const float* basis2     = (const float*)d_in[17];
    const float* att2       = (const float*)d_in[18];
    const float* root2      = (const float*)d_in[19];
    const float* bias2      = (const float*)d_in[20];

    const int N  = in_sizes[0];        // 50000
    const int E  = in_sizes[2];        // 200000
    const int S  = in_sizes[4] / 3;    // 20000
    const int NR = in_sizes[9] / 128;  // 200

    float* ws      = (float*)d_ws;
    float* Y       = ws;                               // [N,640]
    float* X       = Y + (size_t)N * 640;              // [N,128]
    float* Rc      = X + (size_t)N * 128;              // [NR,128]
    int*   deg     = (int*)(Rc + (size_t)NR * 128);    // [N]
    int*   rstart  = deg + N;                          // [N+1]
    int*   cursor  = rstart + N + 1;                   // [N]
    int*   src_s   = cursor + N;                       // [E]
    int*   et_s    = src_s + E;                        // [E]
    float* norm_s  = (float*)(et_s + E);               // [E]

    dim3 ggrid((N + 127) / 128, 5);
    const int egrid = (E + 255) / 256;

    // ---- CSR build (shared by both layers) ----
    hipMemsetAsync(deg, 0, (size_t)N * sizeof(int), stream);
    hist_kernel<<<egrid, 256, 0, stream>>>(edge_index, deg, E);
    scan_kernel<<<1, 1024, 0, stream>>>(deg, rstart, cursor, N);
    fill_kernel<<<egrid, 256, 0, stream>>>(edge_index, edge_type, edge_norm, cursor,
                                           src_s, et_s, norm_s, E);

    // ---- layer 1 ----
    gemm_kernel<true ><<<ggrid, 256, 0, stream>>>(ent_tab, entity, basis1, root1, Y, N);
    gather_kernel<<<(N + 1) / 2, 256, 0, stream>>>(Y, rstart, src_s, et_s, norm_s, att1, bias1, X, N);

    // ---- layer 2 ----
    gemm_kernel<false><<<ggrid, 256, 0, stream>>>(X, nullptr, basis2, root2, Y, N);
    gather_kernel<<<(N + 1) / 2, 256, 0, stream>>>(Y, rstart, src_s, et_s, norm_s, att2, bias2, X, N);

    // ---- relation context ----
    relctx_kernel<<<NR, 128, 0, stream>>>(DAD, rel_tab, Wrel, Rc, NR);

    // ---- gated gather ----
    output_kernel<<<dim3((S + 1) / 2, 3), 256, 0, stream>>>(
        samples, gate_e, gate_r, ent_emb, rel_emb, X, Rc, (float*)d_out, S);
}